// Round 1
// baseline (1336.472 us; speedup 1.0000x reference)
//
#include <hip/hip_runtime.h>

// SlidingWindow: k,v (1, T=2048, H=16, D=64) fp32, W=64
// out_k, out_v: (1, T, H, W, D) fp32, concatenated flat in d_out.
// out[t][h][w][d] = (w <= t) ? in[max(0,t+1-W)+w][h][d] : 0
//
// Pure memory movement: 67 MB write + 17 MB read. One thread per float4,
// each thread handles the same position in both K and V (shared addressing).

constexpr int T  = 2048;
constexpr int H  = 16;
constexpr int W  = 64;
constexpr int D  = 64;
constexpr int D4 = D / 4;                 // 16 float4 per row
constexpr int N4 = T * H * W * D4;        // 2,097,152 float4 per tensor

__global__ __launch_bounds__(256) void SlidingWindow_80771154968643_kernel(
    const float4* __restrict__ k, const float4* __restrict__ v,
    float4* __restrict__ ok, float4* __restrict__ ov) {
    const int idx = blockIdx.x * 256 + threadIdx.x;   // [0, N4)
    const int d4 = idx & (D4 - 1);
    const int w  = (idx >> 4) & (W - 1);
    const int h  = (idx >> 10) & (H - 1);
    const int t  = idx >> 14;

    const int start = max(0, t + 1 - W);
    const bool valid = (w <= t);
    const int src = ((start + w) * H + h) * D4 + d4;  // always in-bounds

    const float4 zero = make_float4(0.f, 0.f, 0.f, 0.f);
    float4 kv = k[src];
    float4 vv = v[src];
    ok[idx] = valid ? kv : zero;
    ov[idx] = valid ? vv : zero;
}

extern "C" void kernel_launch(void* const* d_in, const int* in_sizes, int n_in,
                              void* d_out, int out_size, void* d_ws, size_t ws_size,
                              hipStream_t stream) {
    const float4* k = (const float4*)d_in[0];
    const float4* v = (const float4*)d_in[1];
    float4* ok = (float4*)d_out;
    float4* ov = ok + N4;
    dim3 grid(N4 / 256);
    dim3 block(256);
    SlidingWindow_80771154968643_kernel<<<grid, block, 0, stream>>>(k, v, ok, ov);
}